// Round 8
// baseline (171.809 us; speedup 1.0000x reference)
//
#include <hip/hip_runtime.h>
#include <hip/hip_bf16.h>
#include <math.h>

// MyAttentionHead: B=4, S=2048, d_model=1024, d_head=64. fp32 in/out storage.
// out = ((P~ @ xv) * 1/l) @ O^T.   4-dispatch pipeline:
// K0 wprep (QKV hi/lo transposed + O hi/lo),
// K1 qkv_fused: x @ [Q|K|V] with K=1024 loop in-block (no Cpart round-trip);
//    writes qh/ql/kh/kl row-major + xvP (MFMA-B-frag permuted) directly,
// K2 attn_part: flash attention, 4-way k-split (1024 blocks) -> fp32 partial
//    O slabs [s*2+h2] + partial l [s]   (round-7 verified, unchanged),
// K3 out_fused: reduce 8 slabs (read once) + 1/l -> LDS -> hi/lo frags ->
//    GEMM vs O^T -> fp32 out  (merges round-7's axv_reduce + out_kernel).
#define BATCH 4
#define SEQ   2048
#define DM    1024
#define DH    64
#define NROWS (BATCH*SEQ)   // 8192

typedef __hip_bfloat16 bf16;
typedef __attribute__((ext_vector_type(8))) short short8;
typedef __attribute__((ext_vector_type(8))) unsigned short ushortx8;
typedef __attribute__((ext_vector_type(4))) float floatx4;

__device__ __forceinline__ ushort f2bf(float f) {
    union { bf16 h; ushort u; } cv;
    cv.h = __float2bfloat16(f);
    return cv.u;
}
__device__ __forceinline__ float bf2f(ushort u) {
    union { unsigned int i; float f; } v; v.i = ((unsigned int)u) << 16; return v.f;
}

// async 16B global->LDS: lds dest = wave-uniform base + lane*16
__device__ __forceinline__ void load_lds16(const ushort* g, ushort* l) {
    __builtin_amdgcn_global_load_lds(
        (const __attribute__((address_space(1))) unsigned int*)g,
        (__attribute__((address_space(3))) unsigned int*)l, 16, 0, 0);
}

// ---------------- K0: weight prep ----------------
__global__ __launch_bounds__(256) void wprep_kernel(
    const float* __restrict__ Q, const float* __restrict__ K,
    const float* __restrict__ V, const float* __restrict__ O,
    ushort* __restrict__ WhT, ushort* __restrict__ WlT,
    ushort* __restrict__ Oh, ushort* __restrict__ Ol)
{
    int n = blockIdx.x;                       // 0..255
    if (n < 192) {
        const float* W = (n < 64) ? Q : (n < 128) ? K : V;
        int c = n & 63;
        for (int k = threadIdx.x; k < DM; k += 256) {
            float w = W[k * DH + c];
            ushort hi = f2bf(w);
            WhT[n * DM + k] = hi;
            WlT[n * DM + k] = f2bf(w - bf2f(hi));
        }
    } else {
        int e0 = (n - 192) << 4;              // 16 rows of O per block
        for (int idx = threadIdx.x; idx < 16 * DH; idx += 256) {
            int off = (e0 << 6) + idx;
            float w = O[off];
            ushort hi = f2bf(w);
            Oh[off] = hi;
            Ol[off] = f2bf(w - bf2f(hi));
        }
    }
}

// ---------------- K1: qkv_fused — x @ [Q|K|V], K-loop in-block ----------------
// Block = 32 seq rows, 512 thr = 8 waves: wave = (mh = w>>2, cg = w&3).
// Wave computes rows mh*16.. (16) x cols cg*16.. (16) of each of q,k,v,
// accumulating over the full K=1024 in registers (32 staged iterations).
// Epilogue: hi/lo split -> qh/ql/kh/kl; v -> xvP permuted (ushort4/thread:
// k_local = mh*16+qd*4+r  ->  [c32][qd][h][mh*4+r]).
__global__ __launch_bounds__(512) void qkv_fused_kernel(
    const float* __restrict__ x, const ushort* __restrict__ WhT,
    const ushort* __restrict__ WlT,
    ushort* __restrict__ qh, ushort* __restrict__ ql,
    ushort* __restrict__ kh, ushort* __restrict__ kl, ushort* __restrict__ xvP)
{
    __shared__ __align__(16) ushort Xs[2][32][34];
    __shared__ __align__(16) ushort Ws[2][192][34];
    int s0 = blockIdx.x * 32;
    int t = threadIdx.x;
    int wave = t >> 6, lane = t & 63, m_ = lane & 15, qd = lane >> 4;
    int mh = wave >> 2, cg = wave & 3;
    const floatx4 z4 = {0.f, 0.f, 0.f, 0.f};
    floatx4 accq = z4, acck = z4, accv = z4;
    int xr = t >> 4, xc = (t & 15) * 2;
    for (int k0 = 0; k0 < 1024; k0 += 32) {
        // stage X tile (32 rows x 32 k), hi/lo
        float2 v = *(const float2*)&x[(size_t)(s0 + xr) * DM + k0 + xc];
        ushort h0 = f2bf(v.x), h1 = f2bf(v.y);
        *(ushort2*)&Xs[0][xr][xc] = make_ushort2(h0, h1);
        *(ushort2*)&Xs[1][xr][xc] = make_ushort2(
            f2bf(v.x - bf2f(h0)), f2bf(v.y - bf2f(h1)));
        // stage W tile (192 rows x 32 k, hi+lo): 1536 uint4, 3 per thread
        #pragma unroll
        for (int j = 0; j < 3; ++j) {
            int idx = t + j * 512;            // 0..1535
            int hl = (idx >= 768);
            int r2 = idx - hl * 768;          // 0..767
            int n = r2 >> 2, kc = (r2 & 3) * 8;
            const ushort* src = hl ? WlT : WhT;
            *(uint4*)&Ws[hl][n][kc] = *(const uint4*)&src[n * DM + k0 + kc];
        }
        __syncthreads();
        short8 ah = *(const short8*)&Xs[0][mh * 16 + m_][qd * 8];
        short8 al = *(const short8*)&Xs[1][mh * 16 + m_][qd * 8];
        int nq = cg * 16 + m_, nk = 64 + cg * 16 + m_, nv = 128 + cg * 16 + m_;
        short8 bqh = *(const short8*)&Ws[0][nq][qd * 8];
        short8 bql = *(const short8*)&Ws[1][nq][qd * 8];
        short8 bkh = *(const short8*)&Ws[0][nk][qd * 8];
        short8 bkl = *(const short8*)&Ws[1][nk][qd * 8];
        short8 bvh = *(const short8*)&Ws[0][nv][qd * 8];
        accq = __builtin_amdgcn_mfma_f32_16x16x32_bf16(ah, bqh, accq, 0, 0, 0);
        accq = __builtin_amdgcn_mfma_f32_16x16x32_bf16(al, bqh, accq, 0, 0, 0);
        accq = __builtin_amdgcn_mfma_f32_16x16x32_bf16(ah, bql, accq, 0, 0, 0);
        acck = __builtin_amdgcn_mfma_f32_16x16x32_bf16(ah, bkh, acck, 0, 0, 0);
        acck = __builtin_amdgcn_mfma_f32_16x16x32_bf16(al, bkh, acck, 0, 0, 0);
        acck = __builtin_amdgcn_mfma_f32_16x16x32_bf16(ah, bkl, acck, 0, 0, 0);
        accv = __builtin_amdgcn_mfma_f32_16x16x32_bf16(ah, bvh, accv, 0, 0, 0);
        __syncthreads();
    }
    // epilogue: q,k -> hi/lo row-major; v -> xvP permuted
    int col = cg * 16 + m_;
    #pragma unroll
    for (int r = 0; r < 4; ++r) {
        int row = s0 + mh * 16 + qd * 4 + r;
        ushort hq = f2bf(accq[r]);
        qh[row * 64 + col] = hq;
        ql[row * 64 + col] = f2bf(accq[r] - bf2f(hq));
        ushort hk = f2bf(acck[r]);
        kh[row * 64 + col] = hk;
        kl[row * 64 + col] = f2bf(acck[r] - bf2f(hk));
    }
    int b = s0 >> 11, c32 = (s0 & 2047) >> 5;
    ushort4 v4;
    v4.x = f2bf(accv[0]); v4.y = f2bf(accv[1]);
    v4.z = f2bf(accv[2]); v4.w = f2bf(accv[3]);
    *(ushort4*)&xvP[(size_t)(((b * 64 + c32) * 4 + qd) * 512) + col * 8 + mh * 4] = v4;
}

// ---------------- K2: attn_part — flash attention, 4-way k-split ----------------
// (round-7 verified, unchanged)
__global__ __launch_bounds__(512) void attn_part_kernel(
    const ushort* __restrict__ qh, const ushort* __restrict__ ql,
    const ushort* __restrict__ kh, const ushort* __restrict__ kl,
    const ushort* __restrict__ xvP,
    float* __restrict__ Opart, float* __restrict__ lpart)
{
    __shared__ __align__(16) ushort Kbuf[2][8192];   // [buf][hi 4096 | lo 4096]
    __shared__ __align__(16) ushort xvbuf[2][4096];  // [buf][c32sub][qd][h][j8]
    __shared__ float lred[2][2][16];                 // [tile][h2][q]
    int bid = blockIdx.x;
    int pp = bid & 63, b = (bid >> 6) & 3, s = bid >> 8;
    int srowA = pp << 4, srowB = (127 - pp) << 4;
    int t = threadIdx.x, wave = t >> 6, lane = t & 63, m_ = lane & 15, qd = lane >> 4;
    int nA = (pp >> 2) + 1, nB = ((127 - pp) >> 2) + 1;   // nA < nB always
    int tile = wave >> 2, h2 = (wave >> 1) & 1, nh = wave & 1;
    int srow = tile ? srowB : srowA;
    int nT = tile ? nB : nA;
    int jB = (nB - s + 3) >> 2;       // nB >= 17 > 3 >= s
    const ushort* khb = kh + (((size_t)b << 11)) * 64;
    const ushort* klb = kl + (((size_t)b << 11)) * 64;
    const ushort* xvPb = xvP + ((size_t)b << 17);
    // hoisted Q B-frags: bq[hl][kk]
    short8 bq[2][2];
    {
        size_t qr = (size_t)((b << 11) + srow + m_) * 64 + qd * 8;
        bq[0][0] = *(const short8*)&qh[qr];
        bq[0][1] = *(const short8*)&qh[qr + 32];
        bq[1][0] = *(const short8*)&ql[qr];
        bq[1][1] = *(const short8*)&ql[qr + 32];
    }
    int drow = lane >> 3;                 // 0..7
    int dlc = ((lane & 7) ^ drow) * 8;    // pre-swizzled 16B chunk (ushort units)
    // stage chunk cc into buf: 24 instrs (8 K-hi, 8 K-lo, 8 xv), wave does 3
    #define AT_STAGE(cc, buf)                                                   \
        { int k0r_ = (cc) << 6;                                                 \
          _Pragma("unroll")                                                     \
          for (int i_ = 0; i_ < 3; ++i_) {                                      \
              int c_ = wave * 3 + i_;                                           \
              if (c_ < 8)                                                       \
                  load_lds16(khb + (size_t)(k0r_ + c_ * 8 + drow) * 64 + dlc,   \
                             &Kbuf[buf][c_ * 512]);                             \
              else if (c_ < 16)                                                 \
                  load_lds16(klb + (size_t)(k0r_ + (c_ - 8) * 8 + drow) * 64 + dlc, \
                             &Kbuf[buf][4096 + (c_ - 8) * 512]);                \
              else                                                              \
                  load_lds16(xvPb + (size_t)(cc) * 4096 + (c_ - 16) * 512 + lane * 8, \
                             &xvbuf[buf][(c_ - 16) * 512]);                     \
          } }
    const floatx4 z4 = {0.f, 0.f, 0.f, 0.f};
    floatx4 accO[2] = {z4, z4};
    float ll = 0.f;
    int qrow = srow + m_;
    AT_STAGE(s, 0)
    for (int j = 0; j < jB; ++j) {
        int c = s + 4 * j;
        __syncthreads();
        if (j + 1 < jB) AT_STAGE(s + 4 * (j + 1), (j + 1) & 1)
        if (c < nT) {
            int bufi = j & 1;
            floatx4 accS[2] = {z4, z4};
            #pragma unroll
            for (int kk = 0; kk < 2; ++kk) {
                #pragma unroll
                for (int tt = 0; tt < 2; ++tt) {
                    int row = (2 * h2 + tt) * 16 + m_;
                    int chunk = ((kk << 2) + qd) ^ (m_ & 7);
                    const ushort* ph = &Kbuf[bufi][row * 64 + chunk * 8];
                    short8 akh = *(const short8*)ph;
                    short8 akl = *(const short8*)(ph + 4096);
                    accS[tt] = __builtin_amdgcn_mfma_f32_16x16x32_bf16(akh, bq[0][kk], accS[tt], 0, 0, 0);
                    accS[tt] = __builtin_amdgcn_mfma_f32_16x16x32_bf16(akl, bq[0][kk], accS[tt], 0, 0, 0);
                    accS[tt] = __builtin_amdgcn_mfma_f32_16x16x32_bf16(akh, bq[1][kk], accS[tt], 0, 0, 0);
                }
            }
            float lsum = 0.f;
            short8 pa;
            #pragma unroll
            for (int tt = 0; tt < 2; ++tt) {
                #pragma unroll
                for (int r = 0; r < 4; ++r) {
                    int kc = c * 64 + (2 * h2 + tt) * 16 + qd * 4 + r;
                    float p = (kc <= qrow) ? __expf(accS[tt][r]) : 0.f;
                    lsum += p;
                    pa[tt * 4 + r] = (short)f2bf(p);
                }
            }
            if (nh == 0) ll += lsum;
            const ushort* Xb = &xvbuf[bufi][(h2 * 4 + qd) * 512];
            #pragma unroll
            for (int i = 0; i < 2; ++i) {
                int h = (nh * 2 + i) * 16 + m_;
                short8 xv = *(const short8*)&Xb[h * 8];
                accO[i] = __builtin_amdgcn_mfma_f32_16x16x32_bf16(pa, xv, accO[i], 0, 0, 0);
            }
        }
    }
    // l partial: reduce over qd lanes; (tile,h2) slot from nh==0 waves
    ll += __shfl_xor(ll, 16); ll += __shfl_xor(ll, 32);
    if (qd == 0 && nh == 0) lred[tile][h2][m_] = ll;
    __syncthreads();
    if (t < 32) {
        int tl = t >> 4, q = t & 15;
        int row = (b << 11) + (tl ? srowB : srowA) + q;
        lpart[(size_t)s * NROWS + row] = lred[tl][0][q] + lred[tl][1][q];
    }
    // O partial slab sp = s*2+h2 (disjoint rows/cols per block/wave)
    float* OP = Opart + ((size_t)(s * 2 + h2) * NROWS + (b << 11) + srow) * 64;
    #pragma unroll
    for (int i = 0; i < 2; ++i)
        #pragma unroll
        for (int r = 0; r < 4; ++r)
            OP[(qd * 4 + r) * 64 + (nh * 2 + i) * 16 + m_] = accO[i][r];
    #undef AT_STAGE
}

// ---------------- K3: out_fused — reduce slabs + 1/l, GEMM vs O^T ----------------
// Block = 16 rows, 512 thr. Phase 1: read 8 fp32 slabs ONCE (coalesced),
// scale by 1/l, store fp32 Axv to LDS. Phase 2: each of 8 waves owns a
// 128-col e-slice; build hi/lo A-frags from LDS, 48 MFMA vs Oh/Ol (L2),
// write fp32 out.  (Merges round-7's axv_reduce + out_kernel; identical
// rounding chain: fp32 sum -> *1/l -> bf16 hi/lo -> 3-term MFMA.)
__global__ __launch_bounds__(512) void out_fused_kernel(
    const float* __restrict__ Opart, const float* __restrict__ lpart,
    const ushort* __restrict__ Oh, const ushort* __restrict__ Ol,
    float* __restrict__ out)
{
    __shared__ float Axv[16][68];
    __shared__ float lsc[16];
    int r0 = blockIdx.x * 16;
    int t = threadIdx.x;
    if (t < 16) {
        int rg = r0 + t;
        lsc[t] = 1.f / (lpart[rg] + lpart[NROWS + rg]
                      + lpart[2 * NROWS + rg] + lpart[3 * NROWS + rg]);
    }
    __syncthreads();
    {
        const size_t PSL = (size_t)NROWS * DH;
        size_t e = (size_t)r0 * 64 + t * 2;
        float2 a = *(const float2*)&Opart[e];
        #pragma unroll
        for (int sp = 1; sp < 8; ++sp) {
            float2 w = *(const float2*)&Opart[sp * PSL + e];
            a.x += w.x; a.y += w.y;
        }
        int rr = t >> 5;                 // local row (t*2/64)
        float sc = lsc[rr];
        Axv[rr][(t & 31) * 2]     = a.x * sc;
        Axv[rr][(t & 31) * 2 + 1] = a.y * sc;
    }
    __syncthreads();
    int wave = t >> 6, lane = t & 63, m_ = lane & 15, qd = lane >> 4;
    int e0w = wave << 7;
    short8 Ah[2], Al[2];
    #pragma unroll
    for (int kk = 0; kk < 2; ++kk)
        #pragma unroll
        for (int j = 0; j < 8; ++j) {
            float vv = Axv[m_][kk * 32 + qd * 8 + j];
            ushort hv = f2bf(vv);
            Ah[kk][j] = (short)hv;
            Al[kk][j] = (short)f2bf(vv - bf2f(hv));
        }
    const floatx4 z4 = {0.f, 0.f, 0.f, 0.f};
    floatx4 acc[8] = {z4, z4, z4, z4, z4, z4, z4, z4};
    #pragma unroll
    for (int ni = 0; ni < 8; ++ni) {
        #pragma unroll
        for (int kk = 0; kk < 2; ++kk) {
            size_t boff = (size_t)(e0w + ni * 16 + m_) * 64 + kk * 32 + qd * 8;
            short8 bh = *(const short8*)&Oh[boff];
            short8 bl = *(const short8*)&Ol[boff];
            acc[ni] = __builtin_amdgcn_mfma_f32_16x16x32_bf16(Ah[kk], bh, acc[ni], 0, 0, 0);
            acc[ni] = __builtin_amdgcn_mfma_f32_16x16x32_bf16(Al[kk], bh, acc[ni], 0, 0, 0);
            acc[ni] = __builtin_amdgcn_mfma_f32_16x16x32_bf16(Ah[kk], bl, acc[ni], 0, 0, 0);
        }
    }
    #pragma unroll
    for (int r = 0; r < 4; ++r) {
        float* orow = out + (size_t)(r0 + qd * 4 + r) * DM + e0w;
        #pragma unroll
        for (int ni = 0; ni < 8; ++ni)
            orow[ni * 16 + m_] = acc[ni][r];
    }
}

extern "C" void kernel_launch(void* const* d_in, const int* in_sizes, int n_in,
                              void* d_out, int out_size, void* d_ws, size_t ws_size,
                              hipStream_t stream) {
    const float* x = (const float*)d_in[0];
    const float* Q = (const float*)d_in[1];
    const float* K = (const float*)d_in[2];
    const float* V = (const float*)d_in[3];
    const float* O = (const float*)d_in[4];
    float* out = (float*)d_out;

    char* ws = (char*)d_ws;
    ushort* qh   = (ushort*)(ws);                    // 1 MB [8192][64] bf16
    ushort* ql   = (ushort*)(ws + (1ull  << 20));
    ushort* kh   = (ushort*)(ws + (2ull  << 20));
    ushort* kl   = (ushort*)(ws + (3ull  << 20));
    ushort* xvP  = (ushort*)(ws + (4ull  << 20));    // 1 MB [4][64][4][64][8] permuted xv
    ushort* WhT  = (ushort*)(ws + (5ull  << 20));    // 384 KB [192][1024]
    ushort* WlT  = (ushort*)(ws + (5ull  << 20) + (512ull << 10));
    float*  lpart = (float*)(ws + (6ull  << 20));    // 128 KB [4][8192]
    ushort* Oh   = (ushort*)(ws + (6ull  << 20) + (256ull << 10));  // 128 KB [1024][64]
    ushort* Ol   = (ushort*)(ws + (6ull  << 20) + (384ull << 10));  // 128 KB
    float*  Opart = (float*)(ws + (7ull << 20));     // 16 MB [8][8192][64] fp32

    wprep_kernel<<<256, 256, 0, stream>>>(Q, K, V, O, WhT, WlT, Oh, Ol);
    qkv_fused_kernel<<<NROWS / 32, 512, 0, stream>>>(x, WhT, WlT, qh, ql, kh, kl, xvP);
    attn_part_kernel<<<64 * BATCH * 4, 512, 0, stream>>>(qh, ql, kh, kl, xvP, Opart, lpart);
    out_fused_kernel<<<NROWS / 16, 512, 0, stream>>>(Opart, lpart, Oh, Ol, out);
}